// Round 1
// baseline (11635.825 us; speedup 1.0000x reference)
//
#include <hip/hip_runtime.h>
#include <math.h>

// Semi-relaxed Sinkhorn-Knopp, MI355X.
// B=16, n=4096, k=1024, K=1025. Q = softmax(logits)^10 stored fp32 in d_out
// (dustbin column is constant 1, not stored). One fused pass over Q per
// iteration: per row, dot with b -> a_i, then scatter Q_ij*a_i into per-wave
// LDS column accumulators -> global atomics. Tiny finalize kernel does the
// b-update + err + convergence flag. Final kernel rescales Q in place to the
// plan: a_i * Q_ij * b_j * n.

namespace {
constexpr int   Bn      = 16;
constexpr int   Nn      = 4096;
constexpr int   Kc      = 1024;   // k
constexpr int   KK      = 1025;   // K = k+1 (dustbin)
constexpr int   BSTR    = 1028;   // padded b stride (16B-aligned float4 rows)
constexpr int   ROWS    = Bn * Nn; // 65536
constexpr float EPSI    = 0.1f;
constexpr float PA      = 1.0f / 4096.0f;
constexpr float PB_LOW  = (float)(0.5 / 1024.0);
constexpr float PB_DUST = 0.5f;
constexpr float FI_F    = (float)(1.0 / 1.1);  // GAMMA/(GAMMA+EPS)
constexpr float STOP    = 1e-6f;
constexpr int   NITER   = 100;
} // namespace

__device__ __forceinline__ float wredsum(float v) {
#pragma unroll
  for (int m = 32; m >= 1; m >>= 1) v += __shfl_xor(v, m, 64);
  return v;
}
__device__ __forceinline__ float wredmax(float v) {
#pragma unroll
  for (int m = 32; m >= 1; m >>= 1) v = fmaxf(v, __shfl_xor(v, m, 64));
  return v;
}

// ---------------- init ----------------
__global__ void k_init(float* __restrict__ bvec, float* __restrict__ cacc,
                       float* __restrict__ suma, int* __restrict__ flag) {
  int tid = blockIdx.x * blockDim.x + threadIdx.x;
  int stride = gridDim.x * blockDim.x;
  for (int i = tid; i < Bn * BSTR; i += stride) {
    int j = i % BSTR;
    bvec[i] = (j < KK) ? (float)(1.0 / 1025.0) : 0.0f;
  }
  for (int i = tid; i < Bn * Kc; i += stride) cacc[i] = 0.0f;
  if (tid < Bn) suma[tid] = 0.0f;
  if (tid == 0) *flag = 1;
}

// ---------------- prep: lse + Q = exp((x-lse)/eps) ----------------
// one wave per row (64 lanes x 16 elems)
__global__ __launch_bounds__(256) void k_prep(const float* __restrict__ x,
                                              float* __restrict__ Q) {
  const int wid = threadIdx.x >> 6, lane = threadIdx.x & 63;
  const int row = blockIdx.x * 4 + wid;
  const float4* xp = (const float4*)(x + ((size_t)row << 10));
  float4 v0 = xp[lane], v1 = xp[64 + lane], v2 = xp[128 + lane], v3 = xp[192 + lane];

  float m = fmaxf(fmaxf(fmaxf(v0.x, v0.y), fmaxf(v0.z, v0.w)),
                  fmaxf(fmaxf(fmaxf(v1.x, v1.y), fmaxf(v1.z, v1.w)),
                        fmaxf(fmaxf(fmaxf(v2.x, v2.y), fmaxf(v2.z, v2.w)),
                              fmaxf(fmaxf(v3.x, v3.y), fmaxf(v3.z, v3.w)))));
  m = wredmax(m);

  float s = expf(v0.x - m) + expf(v0.y - m) + expf(v0.z - m) + expf(v0.w - m)
          + expf(v1.x - m) + expf(v1.y - m) + expf(v1.z - m) + expf(v1.w - m)
          + expf(v2.x - m) + expf(v2.y - m) + expf(v2.z - m) + expf(v2.w - m)
          + expf(v3.x - m) + expf(v3.y - m) + expf(v3.z - m) + expf(v3.w - m);
  s = wredsum(s);
  const float lse = m + logf(s);

  float4 q0 = make_float4(expf((v0.x - lse) / EPSI), expf((v0.y - lse) / EPSI),
                          expf((v0.z - lse) / EPSI), expf((v0.w - lse) / EPSI));
  float4 q1 = make_float4(expf((v1.x - lse) / EPSI), expf((v1.y - lse) / EPSI),
                          expf((v1.z - lse) / EPSI), expf((v1.w - lse) / EPSI));
  float4 q2 = make_float4(expf((v2.x - lse) / EPSI), expf((v2.y - lse) / EPSI),
                          expf((v2.z - lse) / EPSI), expf((v2.w - lse) / EPSI));
  float4 q3 = make_float4(expf((v3.x - lse) / EPSI), expf((v3.y - lse) / EPSI),
                          expf((v3.z - lse) / EPSI), expf((v3.w - lse) / EPSI));

  float4* qp = (float4*)(Q + ((size_t)row << 10));
  qp[lane] = q0; qp[64 + lane] = q1; qp[128 + lane] = q2; qp[192 + lane] = q3;
}

// ---------------- fused iteration pass: a-update + column partial sums ----
// 256 threads = 4 waves; each wave owns 16 rows and a private 1024-float LDS
// column accumulator (lane-private slots -> no syncs inside the row loop).
__global__ __launch_bounds__(256) void k_iter(const float* __restrict__ Q,
                                              const float* __restrict__ bvec,
                                              float* __restrict__ avec,
                                              float* __restrict__ cacc,
                                              float* __restrict__ suma,
                                              const int* __restrict__ flag) {
  if (*flag == 0) return;
  __shared__ float cpart[4][1024];
  const int wid = threadIdx.x >> 6, lane = threadIdx.x & 63;
  const int baseRow = blockIdx.x * 64;
  const int batch = baseRow >> 12;
  const int c0 = lane * 4;

#pragma unroll
  for (int s = 0; s < 4; ++s) {
    cpart[wid][s * 256 + c0 + 0] = 0.0f;
    cpart[wid][s * 256 + c0 + 1] = 0.0f;
    cpart[wid][s * 256 + c0 + 2] = 0.0f;
    cpart[wid][s * 256 + c0 + 3] = 0.0f;
  }

  const float4* bp = (const float4*)(bvec + batch * BSTR);
  const float4 b0 = bp[lane], b1 = bp[64 + lane], b2 = bp[128 + lane], b3 = bp[192 + lane];
  const float bdust = bvec[batch * BSTR + 1024];

  float sal = 0.0f;
  const int rowBase = baseRow + wid * 16;
#pragma unroll 1
  for (int r = 0; r < 16; ++r) {
    const int row = rowBase + r;
    const float4* qp = (const float4*)(Q + ((size_t)row << 10));
    const float4 q0 = qp[lane], q1 = qp[64 + lane], q2 = qp[128 + lane], q3 = qp[192 + lane];

    float p = q0.x * b0.x + q0.y * b0.y + q0.z * b0.z + q0.w * b0.w
            + q1.x * b1.x + q1.y * b1.y + q1.z * b1.z + q1.w * b1.w
            + q2.x * b2.x + q2.y * b2.y + q2.z * b2.z + q2.w * b2.w
            + q3.x * b3.x + q3.y * b3.y + q3.z * b3.z + q3.w * b3.w;
    const float inner = wredsum(p) + bdust;
    const float a = PA / inner;
    if (lane == 0) { avec[row] = a; sal += a; }

    cpart[wid][c0 + 0]       += q0.x * a; cpart[wid][c0 + 1]       += q0.y * a;
    cpart[wid][c0 + 2]       += q0.z * a; cpart[wid][c0 + 3]       += q0.w * a;
    cpart[wid][256 + c0 + 0] += q1.x * a; cpart[wid][256 + c0 + 1] += q1.y * a;
    cpart[wid][256 + c0 + 2] += q1.z * a; cpart[wid][256 + c0 + 3] += q1.w * a;
    cpart[wid][512 + c0 + 0] += q2.x * a; cpart[wid][512 + c0 + 1] += q2.y * a;
    cpart[wid][512 + c0 + 2] += q2.z * a; cpart[wid][512 + c0 + 3] += q2.w * a;
    cpart[wid][768 + c0 + 0] += q3.x * a; cpart[wid][768 + c0 + 1] += q3.y * a;
    cpart[wid][768 + c0 + 2] += q3.z * a; cpart[wid][768 + c0 + 3] += q3.w * a;
  }
  if (lane == 0) atomicAdd(&suma[batch], sal);
  __syncthreads();

  const int j = threadIdx.x * 4;
#pragma unroll
  for (int e = 0; e < 4; ++e) {
    const float v = cpart[0][j + e] + cpart[1][j + e] + cpart[2][j + e] + cpart[3][j + e];
    atomicAdd(&cacc[batch * Kc + j + e], v);
  }
}

// ---------------- finalize: b-update, err, flag, clear accumulators -------
__global__ __launch_bounds__(1024) void k_fin(float* __restrict__ bvec,
                                              float* __restrict__ cacc,
                                              float* __restrict__ suma,
                                              int* __restrict__ flag) {
  if (*flag == 0) return;
  const int tid = threadIdx.x;
  float e2 = 0.0f;
  for (int idx = tid; idx < Bn * KK; idx += 1024) {
    const int batch = idx / KK;
    const int j = idx - batch * KK;
    const float bold = bvec[batch * BSTR + j];
    float bnew;
    if (j < Kc) bnew = powf(PB_LOW / cacc[batch * Kc + j], FI_F);
    else        bnew = PB_DUST / suma[batch];
    const float d = bnew - bold;
    e2 += d * d;
    bvec[batch * BSTR + j] = bnew;
  }
  __shared__ float red[16];
  const float v = wredsum(e2);
  if ((tid & 63) == 0) red[tid >> 6] = v;
  __syncthreads();
  if (tid == 0) {
    float t = 0.0f;
    for (int w = 0; w < 16; ++w) t += red[w];
    const float err = sqrtf(t);
    if (!(err > STOP)) *flag = 0;   // NaN also stops, like jnp cond
  }
  __syncthreads();
  for (int idx = tid; idx < Bn * Kc; idx += 1024) cacc[idx] = 0.0f;
  if (tid < Bn) suma[tid] = 0.0f;
}

// ---------------- plan: in-place Q -> a*Q*b*n ----------------
__global__ __launch_bounds__(256) void k_plan(float* __restrict__ Q,
                                              const float* __restrict__ avec,
                                              const float* __restrict__ bvec) {
  const size_t total = (size_t)ROWS * 256;  // float4 count
  const size_t stride = (size_t)gridDim.x * blockDim.x;
  for (size_t idx = (size_t)blockIdx.x * blockDim.x + threadIdx.x; idx < total; idx += stride) {
    const size_t row = idx >> 8;
    const int batch = (int)(row >> 12);
    const int jq = (int)(idx & 255);
    float4 q = ((const float4*)Q)[idx];
    const float4 bb = ((const float4*)(bvec + batch * BSTR))[jq];
    const float sc = avec[row] * 4096.0f;
    q.x *= bb.x * sc; q.y *= bb.y * sc; q.z *= bb.z * sc; q.w *= bb.w * sc;
    ((float4*)Q)[idx] = q;
  }
}

extern "C" void kernel_launch(void* const* d_in, const int* in_sizes, int n_in,
                              void* d_out, int out_size, void* d_ws, size_t ws_size,
                              hipStream_t stream) {
  const float* logits = (const float*)d_in[0];
  float* Q = (float*)d_out;                 // Q lives in d_out until k_plan
  float* ws = (float*)d_ws;
  float* bvec = ws;                          // 16*1028
  float* avec = bvec + Bn * BSTR;            // 65536
  float* cacc = avec + ROWS;                 // 16*1024
  float* suma = cacc + Bn * Kc;              // 16
  int*   flag = (int*)(suma + Bn);           // 1

  k_init<<<64, 256, 0, stream>>>(bvec, cacc, suma, flag);
  k_prep<<<ROWS / 4, 256, 0, stream>>>(logits, Q);
  for (int it = 0; it < NITER; ++it) {
    k_iter<<<ROWS / 64, 256, 0, stream>>>(Q, bvec, avec, cacc, suma, flag);
    k_fin<<<1, 1024, 0, stream>>>(bvec, cacc, suma, flag);
  }
  k_plan<<<4096, 256, 0, stream>>>(Q, avec, bvec);
}

// Round 2
// 8831.381 us; speedup vs baseline: 1.3176x; 1.3176x over previous
//
#include <hip/hip_runtime.h>
#include <hip/hip_bf16.h>
#include <math.h>

// Semi-relaxed Sinkhorn-Knopp, MI355X. B=16, n=4096, k=1024, K=1025.
// R1: Q stored as bf16 (128 MiB, Infinity-Cache-resident) in d_out's first
// half; iteration kernel keeps column partial sums in REGISTERS (no per-row
// LDS RMW -> no bank conflicts); final plan kernel recomputes Q in fp32 from
// logits (re-derives row LSE) so no lse array is needed and output precision
// is unchanged.

namespace {
constexpr int   Bn      = 16;
constexpr int   Kc      = 1024;   // k
constexpr int   KK      = 1025;   // K = k+1 (dustbin)
constexpr int   BSTR    = 1028;   // padded b stride (16B-aligned rows)
constexpr int   ROWS    = Bn * 4096; // 65536
constexpr float INV_EPS = 10.0f;
constexpr float PA      = 1.0f / 4096.0f;
constexpr float PB_LOW  = (float)(0.5 / 1024.0);
constexpr float PB_DUST = 0.5f;
constexpr float FI_F    = (float)(1.0 / 1.1);  // GAMMA/(GAMMA+EPS)
constexpr float STOP    = 1e-6f;
constexpr int   NITER   = 100;
} // namespace

typedef __attribute__((ext_vector_type(8))) unsigned short ushort8;

__device__ __forceinline__ float wredsum(float v) {
#pragma unroll
  for (int m = 32; m >= 1; m >>= 1) v += __shfl_xor(v, m, 64);
  return v;
}
__device__ __forceinline__ float wredmax(float v) {
#pragma unroll
  for (int m = 32; m >= 1; m >>= 1) v = fmaxf(v, __shfl_xor(v, m, 64));
  return v;
}
__device__ __forceinline__ unsigned short f2bf(float x) {
  unsigned int u = __float_as_uint(x);
  return (unsigned short)((u + 0x7FFFu + ((u >> 16) & 1u)) >> 16);  // RNE
}
__device__ __forceinline__ float bf2f(unsigned short h) {
  return __uint_as_float(((unsigned int)h) << 16);
}

// ---------------- init ----------------
__global__ void k_init(float* __restrict__ bvec, float* __restrict__ cacc,
                       float* __restrict__ suma, int* __restrict__ flag) {
  int tid = blockIdx.x * blockDim.x + threadIdx.x;
  int stride = gridDim.x * blockDim.x;
  for (int i = tid; i < Bn * BSTR; i += stride) {
    int j = i % BSTR;
    bvec[i] = (j < KK) ? (float)(1.0 / 1025.0) : 0.0f;
  }
  for (int i = tid; i < Bn * Kc; i += stride) cacc[i] = 0.0f;
  if (tid < Bn) suma[tid] = 0.0f;
  if (tid == 0) *flag = 1;
}

// ---------------- prep: lse + Q(bf16) = exp((x-lse)/eps) ----------------
// one wave per row; lane owns 16 consecutive columns lane*16..lane*16+15
__global__ __launch_bounds__(256) void k_prep(const float* __restrict__ x,
                                              unsigned short* __restrict__ Qb) {
  const int wid = threadIdx.x >> 6, lane = threadIdx.x & 63;
  const int row = blockIdx.x * 4 + wid;
  const float4* xp = (const float4*)(x + ((size_t)row << 10));
  float4 v[4];
#pragma unroll
  for (int s = 0; s < 4; ++s) v[s] = xp[lane * 4 + s];

  float m = -1e30f;
#pragma unroll
  for (int s = 0; s < 4; ++s)
    m = fmaxf(m, fmaxf(fmaxf(v[s].x, v[s].y), fmaxf(v[s].z, v[s].w)));
  m = wredmax(m);

  float sum = 0.0f;
#pragma unroll
  for (int s = 0; s < 4; ++s)
    sum += expf(v[s].x - m) + expf(v[s].y - m) + expf(v[s].z - m) + expf(v[s].w - m);
  sum = wredsum(sum);
  const float lse = m + logf(sum);

  ushort8 q0, q1;
#pragma unroll
  for (int s = 0; s < 2; ++s) {
    q0[s * 4 + 0] = f2bf(expf((v[s].x - lse) * INV_EPS));
    q0[s * 4 + 1] = f2bf(expf((v[s].y - lse) * INV_EPS));
    q0[s * 4 + 2] = f2bf(expf((v[s].z - lse) * INV_EPS));
    q0[s * 4 + 3] = f2bf(expf((v[s].w - lse) * INV_EPS));
  }
#pragma unroll
  for (int s = 0; s < 2; ++s) {
    q1[s * 4 + 0] = f2bf(expf((v[2 + s].x - lse) * INV_EPS));
    q1[s * 4 + 1] = f2bf(expf((v[2 + s].y - lse) * INV_EPS));
    q1[s * 4 + 2] = f2bf(expf((v[2 + s].z - lse) * INV_EPS));
    q1[s * 4 + 3] = f2bf(expf((v[2 + s].w - lse) * INV_EPS));
  }
  ushort8* qp = (ushort8*)(Qb + ((size_t)row << 10));
  qp[lane * 2] = q0;
  qp[lane * 2 + 1] = q1;
}

// ---------------- fused iteration: a-update + column sums in registers ----
__global__ __launch_bounds__(256) void k_iter(const unsigned short* __restrict__ Qb,
                                              const float* __restrict__ bvec,
                                              float* __restrict__ avec,
                                              float* __restrict__ cacc,
                                              float* __restrict__ suma,
                                              const int* __restrict__ flag) {
  if (*flag == 0) return;
  __shared__ float cpart[4][1024];
  const int wid = threadIdx.x >> 6, lane = threadIdx.x & 63;
  const int baseRow = blockIdx.x * 64;
  const int batch = baseRow >> 12;

  const float4* bp = (const float4*)(bvec + batch * BSTR);
  float4 bb[4];
#pragma unroll
  for (int s = 0; s < 4; ++s) bb[s] = bp[lane * 4 + s];
  const float bdust = bvec[batch * BSTR + 1024];

  float acc[16];
#pragma unroll
  for (int e = 0; e < 16; ++e) acc[e] = 0.0f;
  float sal = 0.0f;

  const int rowBase = baseRow + wid * 16;
#pragma unroll 4
  for (int r = 0; r < 16; ++r) {
    const ushort8* qp = (const ushort8*)(Qb + ((size_t)(rowBase + r) << 10));
    const ushort8 qa = qp[lane * 2], qb = qp[lane * 2 + 1];
    float q[16];
#pragma unroll
    for (int e = 0; e < 8; ++e) { q[e] = bf2f(qa[e]); q[8 + e] = bf2f(qb[e]); }

    float p = 0.0f;
#pragma unroll
    for (int s = 0; s < 4; ++s)
      p += q[s * 4 + 0] * bb[s].x + q[s * 4 + 1] * bb[s].y +
           q[s * 4 + 2] * bb[s].z + q[s * 4 + 3] * bb[s].w;

    const float inner = wredsum(p) + bdust;       // dustbin Q == 1
    const float a = PA / inner;                   // broadcast to all lanes
    if (lane == 0) { avec[rowBase + r] = a; sal += a; }
#pragma unroll
    for (int e = 0; e < 16; ++e) acc[e] += q[e] * a;
  }
  if (lane == 0) atomicAdd(&suma[batch], sal);

  // once-per-block cross-wave reduction via LDS, then global atomics
  float4* cp = (float4*)&cpart[wid][lane * 16];
#pragma unroll
  for (int s = 0; s < 4; ++s)
    cp[s] = make_float4(acc[s * 4 + 0], acc[s * 4 + 1], acc[s * 4 + 2], acc[s * 4 + 3]);
  __syncthreads();

  const int j = threadIdx.x * 4;
  const float4 s0 = *(const float4*)&cpart[0][j];
  const float4 s1 = *(const float4*)&cpart[1][j];
  const float4 s2 = *(const float4*)&cpart[2][j];
  const float4 s3 = *(const float4*)&cpart[3][j];
  atomicAdd(&cacc[batch * Kc + j + 0], s0.x + s1.x + s2.x + s3.x);
  atomicAdd(&cacc[batch * Kc + j + 1], s0.y + s1.y + s2.y + s3.y);
  atomicAdd(&cacc[batch * Kc + j + 2], s0.z + s1.z + s2.z + s3.z);
  atomicAdd(&cacc[batch * Kc + j + 3], s0.w + s1.w + s2.w + s3.w);
}

// ---------------- finalize: b-update, err, flag, clear accumulators -------
__global__ __launch_bounds__(1024) void k_fin(float* __restrict__ bvec,
                                              float* __restrict__ cacc,
                                              float* __restrict__ suma,
                                              int* __restrict__ flag) {
  if (*flag == 0) return;
  const int tid = threadIdx.x;
  float e2 = 0.0f;
  for (int idx = tid; idx < Bn * KK; idx += 1024) {
    const int batch = idx / KK;
    const int j = idx - batch * KK;
    const float bold = bvec[batch * BSTR + j];
    float bnew;
    if (j < Kc) bnew = exp2f(FI_F * log2f(PB_LOW / cacc[batch * Kc + j]));
    else        bnew = PB_DUST / suma[batch];
    const float d = bnew - bold;
    e2 += d * d;
    bvec[batch * BSTR + j] = bnew;
  }
  __shared__ float red[16];
  const float v = wredsum(e2);
  if ((tid & 63) == 0) red[tid >> 6] = v;
  __syncthreads();
  if (tid == 0) {
    float t = 0.0f;
    for (int w = 0; w < 16; ++w) t += red[w];
    const float err = sqrtf(t);
    if (!(err > STOP)) *flag = 0;   // NaN also stops, like jnp cond
  }
  __syncthreads();
  for (int idx = tid; idx < Bn * Kc; idx += 1024) cacc[idx] = 0.0f;
  if (tid < Bn) suma[tid] = 0.0f;
}

// ---------------- plan: recompute fp32 Q from logits; out = a*Q*b*n -------
__global__ __launch_bounds__(256) void k_plan(const float* __restrict__ x,
                                              float* __restrict__ out,
                                              const float* __restrict__ avec,
                                              const float* __restrict__ bvec) {
  const int wid = threadIdx.x >> 6, lane = threadIdx.x & 63;
  const int row = blockIdx.x * 4 + wid;
  const int batch = row >> 12;
  const float4* xp = (const float4*)(x + ((size_t)row << 10));
  float4 v[4];
#pragma unroll
  for (int s = 0; s < 4; ++s) v[s] = xp[lane * 4 + s];

  float m = -1e30f;
#pragma unroll
  for (int s = 0; s < 4; ++s)
    m = fmaxf(m, fmaxf(fmaxf(v[s].x, v[s].y), fmaxf(v[s].z, v[s].w)));
  m = wredmax(m);
  float sum = 0.0f;
#pragma unroll
  for (int s = 0; s < 4; ++s)
    sum += expf(v[s].x - m) + expf(v[s].y - m) + expf(v[s].z - m) + expf(v[s].w - m);
  sum = wredsum(sum);
  const float lse = m + logf(sum);

  const float sc = avec[row] * 4096.0f;
  const float4* bp = (const float4*)(bvec + batch * BSTR);
  float4* op = (float4*)(out + ((size_t)row << 10));
#pragma unroll
  for (int s = 0; s < 4; ++s) {
    const float4 b = bp[lane * 4 + s];
    float4 o;
    o.x = expf((v[s].x - lse) * INV_EPS) * sc * b.x;
    o.y = expf((v[s].y - lse) * INV_EPS) * sc * b.y;
    o.z = expf((v[s].z - lse) * INV_EPS) * sc * b.z;
    o.w = expf((v[s].w - lse) * INV_EPS) * sc * b.w;
    op[lane * 4 + s] = o;
  }
}

extern "C" void kernel_launch(void* const* d_in, const int* in_sizes, int n_in,
                              void* d_out, int out_size, void* d_ws, size_t ws_size,
                              hipStream_t stream) {
  const float* logits = (const float*)d_in[0];
  unsigned short* Qb = (unsigned short*)d_out;  // bf16 Q in first half of d_out
  float* ws = (float*)d_ws;
  float* bvec = ws;                          // 16*1028
  float* avec = bvec + Bn * BSTR;            // 65536
  float* cacc = avec + ROWS;                 // 16*1024
  float* suma = cacc + Bn * Kc;              // 16
  int*   flag = (int*)(suma + Bn);           // 1

  k_init<<<64, 256, 0, stream>>>(bvec, cacc, suma, flag);
  k_prep<<<ROWS / 4, 256, 0, stream>>>(logits, Qb);
  for (int it = 0; it < NITER; ++it) {
    k_iter<<<ROWS / 64, 256, 0, stream>>>(Qb, bvec, avec, cacc, suma, flag);
    k_fin<<<1, 1024, 0, stream>>>(bvec, cacc, suma, flag);
  }
  k_plan<<<ROWS / 4, 256, 0, stream>>>(logits, (float*)d_out, avec, bvec);
}

// Round 3
// 3242.897 us; speedup vs baseline: 3.5881x; 2.7233x over previous
//
#include <hip/hip_runtime.h>
#include <hip/hip_bf16.h>
#include <math.h>

// Semi-relaxed Sinkhorn-Knopp, MI355X. B=16, n=4096, k=1024, K=1025.
// R2: no atomics in the iteration path. Each k_iter block writes its 1024
// column partial sums to a private slice part[block][1024]; k_fin (16 blocks,
// one per batch) reduces the 64 partials per column, does the b-update, and
// combines the stopping-test err via a 16-atomic last-block pattern.
// Q stays bf16 (128 MiB, L3-resident) in d_out; plan recomputes fp32 Q.

namespace {
constexpr int   Bn      = 16;
constexpr int   Kc      = 1024;   // k
constexpr int   KK      = 1025;   // K = k+1 (dustbin)
constexpr int   BSTR    = 1028;   // padded b stride (16B-aligned rows)
constexpr int   ROWS    = Bn * 4096; // 65536
constexpr int   NBLK    = ROWS / 64; // 1024 iter blocks, 64 rows each
constexpr float INV_EPS = 10.0f;
constexpr float PA      = 1.0f / 4096.0f;
constexpr float PB_LOW  = (float)(0.5 / 1024.0);
constexpr float PB_DUST = 0.5f;
constexpr float FI_F    = (float)(1.0 / 1.1);  // GAMMA/(GAMMA+EPS)
constexpr float STOP    = 1e-6f;
constexpr int   NITER   = 100;
} // namespace

typedef __attribute__((ext_vector_type(8))) unsigned short ushort8;

__device__ __forceinline__ float wredsum(float v) {
#pragma unroll
  for (int m = 32; m >= 1; m >>= 1) v += __shfl_xor(v, m, 64);
  return v;
}
__device__ __forceinline__ float wredmax(float v) {
#pragma unroll
  for (int m = 32; m >= 1; m >>= 1) v = fmaxf(v, __shfl_xor(v, m, 64));
  return v;
}
__device__ __forceinline__ unsigned short f2bf(float x) {
  unsigned int u = __float_as_uint(x);
  return (unsigned short)((u + 0x7FFFu + ((u >> 16) & 1u)) >> 16);  // RNE
}
__device__ __forceinline__ float bf2f(unsigned short h) {
  return __uint_as_float(((unsigned int)h) << 16);
}

// ---------------- init ----------------
__global__ void k_init(float* __restrict__ bvec, int* __restrict__ cnt,
                       int* __restrict__ flag) {
  int tid = blockIdx.x * blockDim.x + threadIdx.x;
  int stride = gridDim.x * blockDim.x;
  for (int i = tid; i < Bn * BSTR; i += stride) {
    int j = i % BSTR;
    bvec[i] = (j < KK) ? (float)(1.0 / 1025.0) : 0.0f;
  }
  if (tid == 0) { *cnt = 0; *flag = 1; }
}

// ---------------- prep: lse + Q(bf16) = exp((x-lse)/eps) ----------------
__global__ __launch_bounds__(256) void k_prep(const float* __restrict__ x,
                                              unsigned short* __restrict__ Qb) {
  const int wid = threadIdx.x >> 6, lane = threadIdx.x & 63;
  const int row = blockIdx.x * 4 + wid;
  const float4* xp = (const float4*)(x + ((size_t)row << 10));
  float4 v[4];
#pragma unroll
  for (int s = 0; s < 4; ++s) v[s] = xp[lane * 4 + s];

  float m = -1e30f;
#pragma unroll
  for (int s = 0; s < 4; ++s)
    m = fmaxf(m, fmaxf(fmaxf(v[s].x, v[s].y), fmaxf(v[s].z, v[s].w)));
  m = wredmax(m);

  float sum = 0.0f;
#pragma unroll
  for (int s = 0; s < 4; ++s)
    sum += expf(v[s].x - m) + expf(v[s].y - m) + expf(v[s].z - m) + expf(v[s].w - m);
  sum = wredsum(sum);
  const float lse = m + logf(sum);

  ushort8 q0, q1;
#pragma unroll
  for (int s = 0; s < 2; ++s) {
    q0[s * 4 + 0] = f2bf(expf((v[s].x - lse) * INV_EPS));
    q0[s * 4 + 1] = f2bf(expf((v[s].y - lse) * INV_EPS));
    q0[s * 4 + 2] = f2bf(expf((v[s].z - lse) * INV_EPS));
    q0[s * 4 + 3] = f2bf(expf((v[s].w - lse) * INV_EPS));
  }
#pragma unroll
  for (int s = 0; s < 2; ++s) {
    q1[s * 4 + 0] = f2bf(expf((v[2 + s].x - lse) * INV_EPS));
    q1[s * 4 + 1] = f2bf(expf((v[2 + s].y - lse) * INV_EPS));
    q1[s * 4 + 2] = f2bf(expf((v[2 + s].z - lse) * INV_EPS));
    q1[s * 4 + 3] = f2bf(expf((v[2 + s].w - lse) * INV_EPS));
  }
  ushort8* qp = (ushort8*)(Qb + ((size_t)row << 10));
  qp[lane * 2] = q0;
  qp[lane * 2 + 1] = q1;
}

// ---------------- fused iteration: a-update + column sums (no atomics) ----
__global__ __launch_bounds__(256) void k_iter(const unsigned short* __restrict__ Qb,
                                              const float* __restrict__ bvec,
                                              float* __restrict__ avec,
                                              float* __restrict__ part,
                                              float* __restrict__ sumaPart,
                                              const int* __restrict__ flag) {
  if (*flag == 0) return;
  __shared__ float cpart[4][1024];
  __shared__ float sred[4];
  const int wid = threadIdx.x >> 6, lane = threadIdx.x & 63;
  const int baseRow = blockIdx.x * 64;
  const int batch = baseRow >> 12;

  const float4* bp = (const float4*)(bvec + batch * BSTR);
  float4 bb[4];
#pragma unroll
  for (int s = 0; s < 4; ++s) bb[s] = bp[lane * 4 + s];
  const float bdust = bvec[batch * BSTR + 1024];

  float acc[16];
#pragma unroll
  for (int e = 0; e < 16; ++e) acc[e] = 0.0f;
  float sal = 0.0f;

  const int rowBase = baseRow + wid * 16;
#pragma unroll 4
  for (int r = 0; r < 16; ++r) {
    const ushort8* qp = (const ushort8*)(Qb + ((size_t)(rowBase + r) << 10));
    const ushort8 qa = qp[lane * 2], qb = qp[lane * 2 + 1];
    float q[16];
#pragma unroll
    for (int e = 0; e < 8; ++e) { q[e] = bf2f(qa[e]); q[8 + e] = bf2f(qb[e]); }

    float p = 0.0f;
#pragma unroll
    for (int s = 0; s < 4; ++s)
      p += q[s * 4 + 0] * bb[s].x + q[s * 4 + 1] * bb[s].y +
           q[s * 4 + 2] * bb[s].z + q[s * 4 + 3] * bb[s].w;

    const float inner = wredsum(p) + bdust;       // dustbin Q == 1
    const float a = PA / inner;                   // broadcast to all lanes
    if (lane == 0) { avec[rowBase + r] = a; sal += a; }
#pragma unroll
    for (int e = 0; e < 16; ++e) acc[e] += q[e] * a;
  }
  if (lane == 0) sred[wid] = sal;

  float4* cp = (float4*)&cpart[wid][lane * 16];
#pragma unroll
  for (int s = 0; s < 4; ++s)
    cp[s] = make_float4(acc[s * 4 + 0], acc[s * 4 + 1], acc[s * 4 + 2], acc[s * 4 + 3]);
  __syncthreads();

  const int j = threadIdx.x * 4;
  const float4 s0 = *(const float4*)&cpart[0][j];
  const float4 s1 = *(const float4*)&cpart[1][j];
  const float4 s2 = *(const float4*)&cpart[2][j];
  const float4 s3 = *(const float4*)&cpart[3][j];
  float4 o;
  o.x = s0.x + s1.x + s2.x + s3.x;
  o.y = s0.y + s1.y + s2.y + s3.y;
  o.z = s0.z + s1.z + s2.z + s3.z;
  o.w = s0.w + s1.w + s2.w + s3.w;
  ((float4*)(part + ((size_t)blockIdx.x << 10)))[threadIdx.x] = o;
  if (threadIdx.x == 0)
    sumaPart[blockIdx.x] = sred[0] + sred[1] + sred[2] + sred[3];
}

// ---------------- finalize: reduce partials, b-update, err/flag -----------
// 16 blocks (one per batch) x 1024 threads (one per column)
__global__ __launch_bounds__(1024) void k_fin(float* __restrict__ bvec,
                                              const float* __restrict__ part,
                                              const float* __restrict__ sumaPart,
                                              float* __restrict__ e2Part,
                                              int* __restrict__ cnt,
                                              int* __restrict__ flag) {
  if (*flag == 0) return;
  const int b = blockIdx.x;
  const int t = threadIdx.x;

  const float* pp = part + ((size_t)b << 16);   // b*64*1024
  float s = 0.0f;
#pragma unroll 8
  for (int blk = 0; blk < 64; ++blk) s += pp[blk * 1024 + t];

  const float bold = bvec[b * BSTR + t];
  const float bnew = exp2f(FI_F * log2f(PB_LOW / s));
  bvec[b * BSTR + t] = bnew;
  float e2 = (bnew - bold) * (bnew - bold);

  if (t < 64) {                                  // wave 0: dustbin column
    float sa = wredsum(sumaPart[b * 64 + t]);
    if (t == 0) {
      const float bo = bvec[b * BSTR + 1024];
      const float bn = PB_DUST / sa;
      bvec[b * BSTR + 1024] = bn;
      e2 += (bn - bo) * (bn - bo);
    }
  }

  __shared__ float red[16];
  const float v = wredsum(e2);
  if ((t & 63) == 0) red[t >> 6] = v;
  __syncthreads();
  if (t == 0) {
    float tt = 0.0f;
    for (int w = 0; w < 16; ++w) tt += red[w];
    e2Part[b] = tt;
    __threadfence();
    const int old = atomicAdd(cnt, 1);
    if (old == Bn - 1) {                         // last batch-block finishes
      __threadfence();
      float tot = 0.0f;
      for (int w = 0; w < Bn; ++w) tot += e2Part[w];
      const float err = sqrtf(tot);
      if (!(err > STOP)) *flag = 0;              // NaN also stops, like jnp
      *cnt = 0;
    }
  }
}

// ---------------- plan: recompute fp32 Q from logits; out = a*Q*b*n -------
__global__ __launch_bounds__(256) void k_plan(const float* __restrict__ x,
                                              float* __restrict__ out,
                                              const float* __restrict__ avec,
                                              const float* __restrict__ bvec) {
  const int wid = threadIdx.x >> 6, lane = threadIdx.x & 63;
  const int row = blockIdx.x * 4 + wid;
  const int batch = row >> 12;
  const float4* xp = (const float4*)(x + ((size_t)row << 10));
  float4 v[4];
#pragma unroll
  for (int s = 0; s < 4; ++s) v[s] = xp[lane * 4 + s];

  float m = -1e30f;
#pragma unroll
  for (int s = 0; s < 4; ++s)
    m = fmaxf(m, fmaxf(fmaxf(v[s].x, v[s].y), fmaxf(v[s].z, v[s].w)));
  m = wredmax(m);
  float sum = 0.0f;
#pragma unroll
  for (int s = 0; s < 4; ++s)
    sum += expf(v[s].x - m) + expf(v[s].y - m) + expf(v[s].z - m) + expf(v[s].w - m);
  sum = wredsum(sum);
  const float lse = m + logf(sum);

  const float sc = avec[row] * 4096.0f;
  const float4* bp = (const float4*)(bvec + batch * BSTR);
  float4* op = (float4*)(out + ((size_t)row << 10));
#pragma unroll
  for (int s = 0; s < 4; ++s) {
    const float4 b = bp[lane * 4 + s];
    float4 o;
    o.x = expf((v[s].x - lse) * INV_EPS) * sc * b.x;
    o.y = expf((v[s].y - lse) * INV_EPS) * sc * b.y;
    o.z = expf((v[s].z - lse) * INV_EPS) * sc * b.z;
    o.w = expf((v[s].w - lse) * INV_EPS) * sc * b.w;
    op[lane * 4 + s] = o;
  }
}

extern "C" void kernel_launch(void* const* d_in, const int* in_sizes, int n_in,
                              void* d_out, int out_size, void* d_ws, size_t ws_size,
                              hipStream_t stream) {
  const float* logits = (const float*)d_in[0];
  unsigned short* Qb = (unsigned short*)d_out;   // bf16 Q in first half of d_out
  float* ws = (float*)d_ws;
  float* bvec     = ws;                          // 16*1028
  float* avec     = bvec + Bn * BSTR;            // 65536
  float* part     = avec + ROWS;                 // 1024*1024
  float* sumaPart = part + (size_t)NBLK * Kc;    // 1024
  float* e2Part   = sumaPart + NBLK;             // 16
  int*   cnt      = (int*)(e2Part + Bn);         // 1
  int*   flag     = cnt + 1;                     // 1

  k_init<<<64, 256, 0, stream>>>(bvec, cnt, flag);
  k_prep<<<ROWS / 4, 256, 0, stream>>>(logits, Qb);
  for (int it = 0; it < NITER; ++it) {
    k_iter<<<NBLK, 256, 0, stream>>>(Qb, bvec, avec, part, sumaPart, flag);
    k_fin<<<Bn, 1024, 0, stream>>>(bvec, part, sumaPart, e2Part, cnt, flag);
  }
  k_plan<<<ROWS / 4, 256, 0, stream>>>(logits, (float*)d_out, avec, bvec);
}